// Round 1
// baseline (245.732 us; speedup 1.0000x reference)
//
#include <hip/hip_runtime.h>
#include <cstddef>

namespace {

constexpr int kV = 4096;
constexpr int kBlocks = 8 * kV / 16;  // 2048 blocks, 16 v each

typedef float f32x16 __attribute__((ext_vector_type(16)));
typedef float f32x4  __attribute__((ext_vector_type(4)));
typedef short bf16x8 __attribute__((ext_vector_type(8)));

union U8 { unsigned u[4]; uint4 q; bf16x8 v; };

// round-to-nearest-even fp32->bf16, packed pair (a -> lo16, b -> hi16)
__device__ inline unsigned pk_bf16(float a, float b) {
    unsigned ua = __float_as_uint(a);
    unsigned ub = __float_as_uint(b);
    ua = (ua + 0x7FFFu + ((ua >> 16) & 1u)) >> 16;
    ub = (ub + 0x7FFFu + ((ub >> 16) & 1u)) & 0xFFFF0000u;
    return ua | ub;
}

// single-instruction packed RNE fp32->bf16 (gfx950): a -> lo16, b -> hi16
__device__ inline unsigned cvt_pk(float a, float b) {
    unsigned r;
    asm("v_cvt_pk_bf16_f32 %0, %1, %2" : "=v"(r) : "v"(a), "v"(b));
    return r;
}

// fp32 -> bf16 conversion of kernel_weights into d_ws (re-done every launch:
// d_ws is re-poisoned before each timed replay).
__global__ void convW(const float* __restrict__ W, unsigned* __restrict__ Wb) {
    const int i = blockIdx.x * 256 + threadIdx.x;   // 32768 = 65536/2
    const float2 w2 = ((const float2*)W)[i];
    Wb[i] = pk_bf16(w2.x, w2.y);
}

__global__ __launch_bounds__(256, 4)
void fused(const float* __restrict__ signal,
           const int* __restrict__ pidx_g,
           const float* __restrict__ ck_g,
           const unsigned short* __restrict__ Wb,   // bf16 weights from convW
           const float* __restrict__ bias,
           float* __restrict__ out)
{
    // zbf: phase-2 A operand, [g][j], j = c*8 + r*4 + l (pad 512->520 keeps
    // rows 16B-aligned). Each wave writes only its own rows g = vg*4+w, so
    // phase 1 needs NO barriers at all; the single __syncthreads below
    // publishes zbf to the whole block for phase 2.
    __shared__ __align__(16) unsigned short zbf[16][520];   // 16.25 KB

    const int t = threadIdx.x;
    const int b = blockIdx.x >> 8;
    const int v_base = (blockIdx.x & 255) * 16;
    const int w    = t >> 6;
    const int lane = t & 63;
    const int n31  = lane & 31;
    const int h    = lane >> 5;

    const float* sgb = signal + (size_t)b * kV * 64;

    // Hoisted neighbor indices for all 4 wave-private v's (lane p holds vs_p).
    int vsl[4];
    #pragma unroll
    for (int vg = 0; vg < 4; ++vg)
        vsl[vg] = pidx_g[((((size_t)b * kV + v_base + vg * 4 + w) * 32) + n31) * 2 + 1];

    // Prefetch registers for the NEXT vg (issued a full MFMA stage early so
    // global-load latency hides behind frag build + MFMA + epilogue).
    float sP[32];   // gathered signal rows, (p, c=lane)
    float cP[16];   // ck column n31, p in A-frag order

    auto prefetch = [&](int vg) {
        const size_t bv = (size_t)b * kV + (v_base + vg * 4 + w);
        const float* ckv = ck_g + bv * 1024;               // [32 p][32 rn]
        #pragma unroll
        for (int pp = 0; pp < 16; ++pp) {
            const int vs0 = __builtin_amdgcn_readlane(vsl[vg], 2 * pp);
            const int vs1 = __builtin_amdgcn_readlane(vsl[vg], 2 * pp + 1);
            sP[2 * pp    ] = sgb[(size_t)vs0 * 64 + lane];
            sP[2 * pp + 1] = sgb[(size_t)vs1 * 64 + lane];
        }
        #pragma unroll
        for (int j2 = 0; j2 < 4; ++j2) {
            const int p0 = 8 * h + 2 * j2;
            cP[4 * j2 + 0] = ckv[(p0     ) * 32 + n31];
            cP[4 * j2 + 1] = ckv[(p0 +  1) * 32 + n31];
            cP[4 * j2 + 2] = ckv[(p0 + 16) * 32 + n31];
            cP[4 * j2 + 3] = ckv[(p0 + 17) * 32 + n31];
        }
    };

    prefetch(0);

    // ---------------- Phase 1: MFMA 32x32x16, D[m=rn][n=c] ----------------
    #pragma unroll
    for (int vg = 0; vg < 4; ++vg) {
        const int g = vg * 4 + w;                 // wave-private v

        // A[m=rn=n31][k], k = ks*16 + 8h + 2*j2 + {0,1} (same-lane data)
        U8 A0, A1;
        #pragma unroll
        for (int j2 = 0; j2 < 4; ++j2) {
            A0.u[j2] = cvt_pk(cP[4 * j2 + 0], cP[4 * j2 + 1]);
            A1.u[j2] = cvt_pk(cP[4 * j2 + 2], cP[4 * j2 + 3]);
        }

        // Signal p-pairs packed per lane c: pkv[pp] = {p=2pp lo16, p=2pp+1 hi16}
        unsigned pkv[16];
        #pragma unroll
        for (int pp = 0; pp < 16; ++pp)
            pkv[pp] = cvt_pk(sP[2 * pp], sP[2 * pp + 1]);

        if (vg < 3) prefetch(vg + 1);   // issue next loads into freed regs

        // B[k=p][n=c] frags via in-register half-wave swaps (no LDS, no sync):
        //   permlane32_swap(x,y): ret0 = {x.lanes0-31, y.lanes0-31},
        //                         ret1 = {x.lanes32-63, y.lanes32-63}
        // Lane (n31,h=0) of B00 needs (p=2j2 pair, c=n31)   = local pkv[j2]
        // Lane (n31,h=1) of B00 needs (p=8+2j2 pair, c=n31) = lane n31's pkv[4+j2]
        // B01 is the complementary hi-half pair (c = n31+32).
        U8 B00, B01, B10, B11;
        #pragma unroll
        for (int j2 = 0; j2 < 4; ++j2) {
            auto r0 = __builtin_amdgcn_permlane32_swap(pkv[j2], pkv[4 + j2], false, false);
            B00.u[j2] = r0[0];
            B01.u[j2] = r0[1];
            auto r1 = __builtin_amdgcn_permlane32_swap(pkv[8 + j2], pkv[12 + j2], false, false);
            B10.u[j2] = r1[0];
            B11.u[j2] = r1[1];
        }

        f32x16 acc0, acc1;
        #pragma unroll
        for (int j = 0; j < 16; ++j) { acc0[j] = 0.f; acc1[j] = 0.f; }
        acc0 = __builtin_amdgcn_mfma_f32_32x32x16_bf16(A0.v, B00.v, acc0, 0, 0, 0);
        acc1 = __builtin_amdgcn_mfma_f32_32x32x16_bf16(A0.v, B01.v, acc1, 0, 0, 0);
        acc0 = __builtin_amdgcn_mfma_f32_32x32x16_bf16(A1.v, B10.v, acc0, 0, 0, 0);
        acc1 = __builtin_amdgcn_mfma_f32_32x32x16_bf16(A1.v, B11.v, acc1, 0, 0, 0);

        // C-layout: col=lane&31 (=c), row=(reg&3)+8*(reg>>2)+4*h (=rn=r*16+n).
        #pragma unroll
        for (int ct = 0; ct < 2; ++ct) {
            const f32x16 a = ct ? acc1 : acc0;
            float s[16];
            #pragma unroll
            for (int j = 0; j < 16; ++j) s[j] = a[j] * a[j];
            // h=0 rows {0-3,8-11,16-19,24-27}; h=1 rows {4-7,12-15,20-23,28-31}
            const float o00 = s[0], o10 = s[1] + s[2] + s[3];
            const float o20 = s[4], o30 = s[5] + s[6] + s[7];
            const float o01 = s[8], o11 = s[9] + s[10] + s[11];
            const float o21 = s[12], o31 = s[13] + s[14] + s[15];
            const float x0 = s[0] + s[1] + s[2] + s[3];
            const float x1 = s[4] + s[5] + s[6] + s[7];
            const float x2 = s[8] + s[9] + s[10] + s[11];
            const float x3 = s[12] + s[13] + s[14] + s[15];
            const float e0 = __shfl_xor(h ? x0 : o20, 32);
            const float e1 = __shfl_xor(h ? x1 : o30, 32);
            const float e2 = __shfl_xor(h ? x2 : o21, 32);
            const float e3 = __shfl_xor(h ? x3 : o31, 32);
            if (h == 0) {
                const float z00 = sqrtf(fmaxf(o00,      1e-4f));
                const float z10 = sqrtf(fmaxf(o10,      1e-4f));
                const float z20 = sqrtf(fmaxf(o20 + e0, 1e-4f));
                const float z30 = sqrtf(fmaxf(o30 + e1, 1e-4f));
                const float z01 = sqrtf(fmaxf(o01,      1e-4f));
                const float z11 = sqrtf(fmaxf(o11,      1e-4f));
                const float z21 = sqrtf(fmaxf(o21 + e2, 1e-4f));
                const float z31 = sqrtf(fmaxf(o31 + e3, 1e-4f));
                uint4 d;
                d.x = cvt_pk(z00, z10);
                d.y = cvt_pk(z20, z30);
                d.z = cvt_pk(z01, z11);
                d.w = cvt_pk(z21, z31);
                *(uint4*)&zbf[g][(n31 + 32 * ct) * 8] = d;   // j = c*8+r*4+l
            }
        }
    }
    __syncthreads();   // zbf complete, visible to all waves

    // ------- Phase 2: MFMA 16x16x32, D[m=g][n=i], K=512, B = bf16 global ---
    const int m15 = lane & 15;          // A row g AND D col i
    const int q   = lane >> 4;          // k-quad
    f32x4 pa0, pa1;
    #pragma unroll
    for (int j = 0; j < 4; ++j) { pa0[j] = 0.f; pa1[j] = 0.f; }
    const int i0 = w * 32 + m15;
    const int i1 = w * 32 + 16 + m15;
    #pragma unroll 4
    for (int ks = 0; ks < 16; ++ks) {
        U8 Az, Bw0, Bw1;
        Az.q  = *(const uint4*)&zbf[m15][ks * 32 + q * 8];
        Bw0.q = *(const uint4*)&Wb[(size_t)i0 * 512 + ks * 32 + q * 8];
        Bw1.q = *(const uint4*)&Wb[(size_t)i1 * 512 + ks * 32 + q * 8];
        pa0 = __builtin_amdgcn_mfma_f32_16x16x32_bf16(Az.v, Bw0.v, pa0, 0, 0, 0);
        pa1 = __builtin_amdgcn_mfma_f32_16x16x32_bf16(Az.v, Bw1.v, pa1, 0, 0, 0);
    }
    const float bi0 = bias[i0], bi1 = bias[i1];
    #pragma unroll
    for (int reg = 0; reg < 4; ++reg) {
        const int g = q * 4 + reg;                       // D row = g
        const size_t row = ((size_t)b * kV + v_base + g) * 128;
        out[row + i0] = fmaxf(pa0[reg] + bi0, 0.f);
        out[row + i1] = fmaxf(pa1[reg] + bi1, 0.f);
    }
}

} // namespace

extern "C" void kernel_launch(void* const* d_in, const int* in_sizes, int n_in,
                              void* d_out, int out_size, void* d_ws, size_t ws_size,
                              hipStream_t stream) {
    const float* signal = (const float*)d_in[0];
    const int*   pidx   = (const int*)d_in[1];
    const float* ck     = (const float*)d_in[2];
    const float* W      = (const float*)d_in[3];
    const float* bias   = (const float*)d_in[4];
    float* out = (float*)d_out;
    unsigned* Wb = (unsigned*)d_ws;     // 128 KB bf16 weights

    convW<<<dim3(128), dim3(256), 0, stream>>>(W, Wb);
    fused<<<dim3(kBlocks), dim3(256), 0, stream>>>(
        signal, pidx, ck, (const unsigned short*)Wb, bias, out);
}

// Round 2
// 243.920 us; speedup vs baseline: 1.0074x; 1.0074x over previous
//
#include <hip/hip_runtime.h>
#include <cstddef>

namespace {

constexpr int kV = 4096;
constexpr int kBlocks = 8 * kV / 16;  // 2048 blocks, 16 v each

typedef float f32x16 __attribute__((ext_vector_type(16)));
typedef float f32x4  __attribute__((ext_vector_type(4)));
typedef short bf16x8 __attribute__((ext_vector_type(8)));

union U8 { unsigned u[4]; uint4 q; bf16x8 v; };

// round-to-nearest-even fp32->bf16, packed pair (a -> lo16, b -> hi16)
__device__ inline unsigned pk_bf16(float a, float b) {
    unsigned ua = __float_as_uint(a);
    unsigned ub = __float_as_uint(b);
    ua = (ua + 0x7FFFu + ((ua >> 16) & 1u)) >> 16;
    ub = (ub + 0x7FFFu + ((ub >> 16) & 1u)) & 0xFFFF0000u;
    return ua | ub;
}

// single-instruction packed RNE fp32->bf16 (gfx950): a -> lo16, b -> hi16.
// Same rounding as pk_bf16 but 1 VALU op instead of ~5.
__device__ inline unsigned cvt_pk(float a, float b) {
    unsigned r;
    asm("v_cvt_pk_bf16_f32 %0, %1, %2" : "=v"(r) : "v"(a), "v"(b));
    return r;
}

// fp32 -> bf16 conversion of kernel_weights into d_ws (re-done every launch:
// d_ws is re-poisoned before each timed replay).
__global__ void convW(const float* __restrict__ W, unsigned* __restrict__ Wb) {
    const int i = blockIdx.x * 256 + threadIdx.x;   // 32768 = 65536/2
    const float2 w2 = ((const float2*)W)[i];
    Wb[i] = pk_bf16(w2.x, w2.y);
}

__global__ __launch_bounds__(256, 4)
void fused(const float* __restrict__ signal,
           const int* __restrict__ pidx_g,
           const float* __restrict__ ck_g,
           const unsigned short* __restrict__ Wb,   // bf16 weights from convW
           const float* __restrict__ bias,
           float* __restrict__ out)
{
    // zbf: phase-2 A operand, [g][j], j = c*8 + r*4 + l (pad 512->520 keeps
    // rows 16B-aligned). patchI: per-WAVE p-pair-interleaved signal tile,
    // dword = {p even lo16, p odd hi16}; row pp holds k-pair (2pp,2pp+1),
    // col = channel c.
    // patchI[w] is wave-private: a wave's ds_read after its own ds_write is
    // ordered by the in-order per-wave LDS pipe, so phase 1 needs NO
    // __syncthreads (removing the 8 per-vg barriers un-lockstops the 4 waves
    // and lets the prefetch actually hide global-load latency). The single
    // barrier below publishes zbf cross-wave for phase 2.
    __shared__ __align__(16) unsigned short zbf[16][520];   // 16.25 KB
    __shared__ unsigned patchI[4][16][64];                  // 16 KB

    const int t = threadIdx.x;
    const int b = blockIdx.x >> 8;
    const int v_base = (blockIdx.x & 255) * 16;
    const int w    = t >> 6;
    const int lane = t & 63;
    const int n31  = lane & 31;
    const int h    = lane >> 5;

    unsigned (*pI)[64] = patchI[w];
    const float* sgb = signal + (size_t)b * kV * 64;

    // Hoisted neighbor indices for all 4 wave-private v's (lane p holds vs_p).
    int vsl[4];
    #pragma unroll
    for (int vg = 0; vg < 4; ++vg)
        vsl[vg] = pidx_g[((((size_t)b * kV + v_base + vg * 4 + w) * 32) + n31) * 2 + 1];

    // Prefetch registers for the NEXT vg (issued ~a full MFMA stage early so
    // global-load latency hides behind frag reads + MFMA + epilogue). sP dies
    // into LDS before the next prefetch -> live set stays within 64 VGPRs
    // (round-1 lesson: keeping the B-frags in regs across prefetch spills
    // ~33 MB of scratch traffic).
    float sP[32];   // gathered signal rows, (p, c=lane)
    float cP[16];   // ck column n31, p in A-frag order

    auto prefetch = [&](int vg) {
        const size_t bv = (size_t)b * kV + (v_base + vg * 4 + w);
        const float* ckv = ck_g + bv * 1024;               // [32 p][32 rn]
        #pragma unroll
        for (int pp = 0; pp < 16; ++pp) {
            const int vs0 = __builtin_amdgcn_readlane(vsl[vg], 2 * pp);
            const int vs1 = __builtin_amdgcn_readlane(vsl[vg], 2 * pp + 1);
            sP[2 * pp    ] = sgb[(size_t)vs0 * 64 + lane];
            sP[2 * pp + 1] = sgb[(size_t)vs1 * 64 + lane];
        }
        #pragma unroll
        for (int j2 = 0; j2 < 4; ++j2) {
            const int p0 = 8 * h + 2 * j2;
            cP[4 * j2 + 0] = ckv[(p0     ) * 32 + n31];
            cP[4 * j2 + 1] = ckv[(p0 +  1) * 32 + n31];
            cP[4 * j2 + 2] = ckv[(p0 + 16) * 32 + n31];
            cP[4 * j2 + 3] = ckv[(p0 + 17) * 32 + n31];
        }
    };

    prefetch(0);

    // ---------------- Phase 1: MFMA 32x32x16, D[m=rn][n=c] ----------------
    #pragma unroll
    for (int vg = 0; vg < 4; ++vg) {
        const int g = vg * 4 + w;                 // wave-private v

        // consume prefetch: stage signal (bf16 p-pairs) + build A-frags
        #pragma unroll
        for (int pp = 0; pp < 16; ++pp)
            pI[pp][lane] = cvt_pk(sP[2 * pp], sP[2 * pp + 1]);

        // A[m=rn=n31][k], k = ks*16 + 8h + 2*j2 + {0,1} (same-lane data)
        U8 A0, A1;
        #pragma unroll
        for (int j2 = 0; j2 < 4; ++j2) {
            A0.u[j2] = cvt_pk(cP[4 * j2 + 0], cP[4 * j2 + 1]);
            A1.u[j2] = cvt_pk(cP[4 * j2 + 2], cP[4 * j2 + 3]);
        }

        if (vg < 3) prefetch(vg + 1);   // issue next loads into freed regs

        // B[k][n=c] frags from wave-private LDS (in-order LDS pipe: no sync)
        U8 B00, B01, B10, B11;   // c-tiles 0..31 / 32..63
        #pragma unroll
        for (int j2 = 0; j2 < 4; ++j2) {
            B00.u[j2] = pI[    4 * h + j2][n31];
            B01.u[j2] = pI[    4 * h + j2][n31 + 32];
            B10.u[j2] = pI[8 + 4 * h + j2][n31];
            B11.u[j2] = pI[8 + 4 * h + j2][n31 + 32];
        }

        f32x16 acc0, acc1;
        #pragma unroll
        for (int j = 0; j < 16; ++j) { acc0[j] = 0.f; acc1[j] = 0.f; }
        acc0 = __builtin_amdgcn_mfma_f32_32x32x16_bf16(A0.v, B00.v, acc0, 0, 0, 0);
        acc1 = __builtin_amdgcn_mfma_f32_32x32x16_bf16(A0.v, B01.v, acc1, 0, 0, 0);
        acc0 = __builtin_amdgcn_mfma_f32_32x32x16_bf16(A1.v, B10.v, acc0, 0, 0, 0);
        acc1 = __builtin_amdgcn_mfma_f32_32x32x16_bf16(A1.v, B11.v, acc1, 0, 0, 0);

        // C-layout: col=lane&31 (=c), row=(reg&3)+8*(reg>>2)+4*h (=rn=r*16+n).
        #pragma unroll
        for (int ct = 0; ct < 2; ++ct) {
            const f32x16 a = ct ? acc1 : acc0;
            float s[16];
            #pragma unroll
            for (int j = 0; j < 16; ++j) s[j] = a[j] * a[j];
            // h=0 rows {0-3,8-11,16-19,24-27}; h=1 rows {4-7,12-15,20-23,28-31}
            const float o00 = s[0], o10 = s[1] + s[2] + s[3];
            const float o20 = s[4], o30 = s[5] + s[6] + s[7];
            const float o01 = s[8], o11 = s[9] + s[10] + s[11];
            const float o21 = s[12], o31 = s[13] + s[14] + s[15];
            const float x0 = s[0] + s[1] + s[2] + s[3];
            const float x1 = s[4] + s[5] + s[6] + s[7];
            const float x2 = s[8] + s[9] + s[10] + s[11];
            const float x3 = s[12] + s[13] + s[14] + s[15];
            const float e0 = __shfl_xor(h ? x0 : o20, 32);
            const float e1 = __shfl_xor(h ? x1 : o30, 32);
            const float e2 = __shfl_xor(h ? x2 : o21, 32);
            const float e3 = __shfl_xor(h ? x3 : o31, 32);
            if (h == 0) {
                const float z00 = sqrtf(fmaxf(o00,      1e-4f));
                const float z10 = sqrtf(fmaxf(o10,      1e-4f));
                const float z20 = sqrtf(fmaxf(o20 + e0, 1e-4f));
                const float z30 = sqrtf(fmaxf(o30 + e1, 1e-4f));
                const float z01 = sqrtf(fmaxf(o01,      1e-4f));
                const float z11 = sqrtf(fmaxf(o11,      1e-4f));
                const float z21 = sqrtf(fmaxf(o21 + e2, 1e-4f));
                const float z31 = sqrtf(fmaxf(o31 + e3, 1e-4f));
                uint4 d;
                d.x = cvt_pk(z00, z10);
                d.y = cvt_pk(z20, z30);
                d.z = cvt_pk(z01, z11);
                d.w = cvt_pk(z21, z31);
                *(uint4*)&zbf[g][(n31 + 32 * ct) * 8] = d;   // j = c*8+r*4+l
            }
        }
    }
    __syncthreads();   // zbf complete, visible to all waves

    // ------- Phase 2: MFMA 16x16x32, D[m=g][n=i], K=512, B = bf16 global ---
    const int m15 = lane & 15;          // A row g AND D col i
    const int q   = lane >> 4;          // k-quad
    f32x4 pa0, pa1;
    #pragma unroll
    for (int j = 0; j < 4; ++j) { pa0[j] = 0.f; pa1[j] = 0.f; }
    const int i0 = w * 32 + m15;
    const int i1 = w * 32 + 16 + m15;
    #pragma unroll 4
    for (int ks = 0; ks < 16; ++ks) {
        U8 Az, Bw0, Bw1;
        Az.q  = *(const uint4*)&zbf[m15][ks * 32 + q * 8];
        Bw0.q = *(const uint4*)&Wb[(size_t)i0 * 512 + ks * 32 + q * 8];
        Bw1.q = *(const uint4*)&Wb[(size_t)i1 * 512 + ks * 32 + q * 8];
        pa0 = __builtin_amdgcn_mfma_f32_16x16x32_bf16(Az.v, Bw0.v, pa0, 0, 0, 0);
        pa1 = __builtin_amdgcn_mfma_f32_16x16x32_bf16(Az.v, Bw1.v, pa1, 0, 0, 0);
    }
    const float bi0 = bias[i0], bi1 = bias[i1];
    #pragma unroll
    for (int reg = 0; reg < 4; ++reg) {
        const int g = q * 4 + reg;                       // D row = g
        const size_t row = ((size_t)b * kV + v_base + g) * 128;
        out[row + i0] = fmaxf(pa0[reg] + bi0, 0.f);
        out[row + i1] = fmaxf(pa1[reg] + bi1, 0.f);
    }
}

} // namespace

extern "C" void kernel_launch(void* const* d_in, const int* in_sizes, int n_in,
                              void* d_out, int out_size, void* d_ws, size_t ws_size,
                              hipStream_t stream) {
    const float* signal = (const float*)d_in[0];
    const int*   pidx   = (const int*)d_in[1];
    const float* ck     = (const float*)d_in[2];
    const float* W      = (const float*)d_in[3];
    const float* bias   = (const float*)d_in[4];
    float* out = (float*)d_out;
    unsigned* Wb = (unsigned*)d_ws;     // 128 KB bf16 weights

    convW<<<dim3(128), dim3(256), 0, stream>>>(W, Wb);
    fused<<<dim3(kBlocks), dim3(256), 0, stream>>>(
        signal, pidx, ck, (const unsigned short*)Wb, bias, out);
}

// Round 3
// 236.744 us; speedup vs baseline: 1.0380x; 1.0303x over previous
//
#include <hip/hip_runtime.h>
#include <cstddef>

namespace {

constexpr int kV = 4096;
constexpr int kBlocks = 8 * kV / 16;  // 2048 blocks, 16 v each

typedef float f32x16 __attribute__((ext_vector_type(16)));
typedef float f32x4  __attribute__((ext_vector_type(4)));
typedef short bf16x8 __attribute__((ext_vector_type(8)));

union U8 { unsigned u[4]; uint4 q; bf16x8 v; };

// round-to-nearest-even fp32->bf16, packed pair (a -> lo16, b -> hi16)
__device__ inline unsigned pk_bf16(float a, float b) {
    unsigned ua = __float_as_uint(a);
    unsigned ub = __float_as_uint(b);
    ua = (ua + 0x7FFFu + ((ua >> 16) & 1u)) >> 16;
    ub = (ub + 0x7FFFu + ((ub >> 16) & 1u)) & 0xFFFF0000u;
    return ua | ub;
}

// single-instruction packed RNE fp32->bf16 (gfx950): a -> lo16, b -> hi16.
__device__ inline unsigned cvt_pk(float a, float b) {
    unsigned r;
    asm("v_cvt_pk_bf16_f32 %0, %1, %2" : "=v"(r) : "v"(a), "v"(b));
    return r;
}

// fp32 -> bf16 conversion of kernel_weights into d_ws (re-done every launch:
// d_ws is re-poisoned before each timed replay).
__global__ void convW(const float* __restrict__ W, unsigned* __restrict__ Wb) {
    const int i = blockIdx.x * 256 + threadIdx.x;   // 32768 = 65536/2
    const float2 w2 = ((const float2*)W)[i];
    Wb[i] = pk_bf16(w2.x, w2.y);
}

// launch_bounds(256, 2): min 2 waves/EU -> VGPR budget 256. Occupancy is
// LDS-capped at 4 blocks/CU (33.25 KB) as long as VGPR <= 128; the old
// (256, 4) bound made the allocator spill ~19 MB of scratch per dispatch
// (rounds 1-2: WRITE_SIZE 16384 -> 26624/34816 KB) rather than grow past 64.
__global__ __launch_bounds__(256, 2)
void fused(const float* __restrict__ signal,
           const int* __restrict__ pidx_g,
           const float* __restrict__ ck_g,
           const unsigned short* __restrict__ Wb,   // bf16 weights from convW
           const float* __restrict__ bias,
           float* __restrict__ out)
{
    // zbf: phase-2 A operand, [g][j], j = c*8 + r*4 + l (pad 512->520 keeps
    // rows 16B-aligned). patchI: per-WAVE p-pair-interleaved signal tile,
    // dword = {p even lo16, p odd hi16}; row pp holds k-pair (2pp,2pp+1),
    // col = channel c.
    // patchI[w] is wave-private: a wave's ds_read after its own ds_write is
    // ordered by the in-order per-wave LDS pipe, so phase 1 needs NO
    // __syncthreads (a barrier would also drain vmcnt, killing the 2-stage
    // ck prefetch distance). The single barrier below publishes zbf
    // cross-wave for phase 2.
    __shared__ __align__(16) unsigned short zbf[16][520];   // 16.25 KB
    __shared__ unsigned patchI[4][16][64];                  // 16 KB

    const int t = threadIdx.x;
    const int b = blockIdx.x >> 8;
    const int v_base = (blockIdx.x & 255) * 16;
    const int w    = t >> 6;
    const int lane = t & 63;
    const int n31  = lane & 31;
    const int h    = lane >> 5;

    unsigned (*pI)[64] = patchI[w];
    const float* sgb = signal + (size_t)b * kV * 64;

    // Hoisted neighbor indices for all 4 wave-private v's (lane p holds vs_p).
    int vsl[4];
    #pragma unroll
    for (int vg = 0; vg < 4; ++vg)
        vsl[vg] = pidx_g[((((size_t)b * kV + v_base + vg * 4 + w) * 32) + n31) * 2 + 1];

    // Prefetch registers. Signal gather (L2/L3-resident, ~200-450 cyc) is
    // 1 stage deep; ck (pure HBM stream, ~900 cyc) is 2 stages deep via a
    // ping-pong buffer. All cP indices are unroll-time constants (a runtime
    // index would demote the array to scratch).
    float sP[32];       // gathered signal rows, (p, c=lane)
    float cP[2][16];    // ck column n31, p in A-frag order, 2 stages

    auto prefetch_sig = [&](int vg) {
        #pragma unroll
        for (int pp = 0; pp < 16; ++pp) {
            const int vs0 = __builtin_amdgcn_readlane(vsl[vg], 2 * pp);
            const int vs1 = __builtin_amdgcn_readlane(vsl[vg], 2 * pp + 1);
            sP[2 * pp    ] = sgb[(size_t)vs0 * 64 + lane];
            sP[2 * pp + 1] = sgb[(size_t)vs1 * 64 + lane];
        }
    };
    auto prefetch_ck = [&](int vg, int buf) {
        const size_t bv = (size_t)b * kV + (v_base + vg * 4 + w);
        const float* ckv = ck_g + bv * 1024;               // [32 p][32 rn]
        #pragma unroll
        for (int j2 = 0; j2 < 4; ++j2) {
            const int p0 = 8 * h + 2 * j2;
            cP[buf][4 * j2 + 0] = ckv[(p0     ) * 32 + n31];
            cP[buf][4 * j2 + 1] = ckv[(p0 +  1) * 32 + n31];
            cP[buf][4 * j2 + 2] = ckv[(p0 + 16) * 32 + n31];
            cP[buf][4 * j2 + 3] = ckv[(p0 + 17) * 32 + n31];
        }
    };

    prefetch_ck(0, 0);
    prefetch_sig(0);
    prefetch_ck(1, 1);

    // ---------------- Phase 1: MFMA 32x32x16, D[m=rn][n=c] ----------------
    #pragma unroll
    for (int vg = 0; vg < 4; ++vg) {
        const int g = vg * 4 + w;                 // wave-private v
        const int cur = vg & 1;

        // consume signal prefetch: stage bf16 p-pairs (sP dies here)
        #pragma unroll
        for (int pp = 0; pp < 16; ++pp)
            pI[pp][lane] = cvt_pk(sP[2 * pp], sP[2 * pp + 1]);

        // A[m=rn=n31][k], k = ks*16 + 8h + 2*j2 + {0,1}; cP[cur] dies here
        U8 A0, A1;
        #pragma unroll
        for (int j2 = 0; j2 < 4; ++j2) {
            A0.u[j2] = cvt_pk(cP[cur][4 * j2 + 0], cP[cur][4 * j2 + 1]);
            A1.u[j2] = cvt_pk(cP[cur][4 * j2 + 2], cP[cur][4 * j2 + 3]);
        }

        // refill into the freed registers
        if (vg < 3) prefetch_sig(vg + 1);
        if (vg < 2) prefetch_ck(vg + 2, cur);

        // B[k][n=c] frags from wave-private LDS (in-order LDS pipe: no sync)
        U8 B00, B01, B10, B11;   // c-tiles 0..31 / 32..63
        #pragma unroll
        for (int j2 = 0; j2 < 4; ++j2) {
            B00.u[j2] = pI[    4 * h + j2][n31];
            B01.u[j2] = pI[    4 * h + j2][n31 + 32];
            B10.u[j2] = pI[8 + 4 * h + j2][n31];
            B11.u[j2] = pI[8 + 4 * h + j2][n31 + 32];
        }

        f32x16 acc0, acc1;
        #pragma unroll
        for (int j = 0; j < 16; ++j) { acc0[j] = 0.f; acc1[j] = 0.f; }
        acc0 = __builtin_amdgcn_mfma_f32_32x32x16_bf16(A0.v, B00.v, acc0, 0, 0, 0);
        acc1 = __builtin_amdgcn_mfma_f32_32x32x16_bf16(A0.v, B01.v, acc1, 0, 0, 0);
        acc0 = __builtin_amdgcn_mfma_f32_32x32x16_bf16(A1.v, B10.v, acc0, 0, 0, 0);
        acc1 = __builtin_amdgcn_mfma_f32_32x32x16_bf16(A1.v, B11.v, acc1, 0, 0, 0);

        // C-layout: col=lane&31 (=c), row=(reg&3)+8*(reg>>2)+4*h (=rn=r*16+n).
        #pragma unroll
        for (int ct = 0; ct < 2; ++ct) {
            const f32x16 a = ct ? acc1 : acc0;
            float s[16];
            #pragma unroll
            for (int j = 0; j < 16; ++j) s[j] = a[j] * a[j];
            // h=0 rows {0-3,8-11,16-19,24-27}; h=1 rows {4-7,12-15,20-23,28-31}
            const float o00 = s[0], o10 = s[1] + s[2] + s[3];
            const float o20 = s[4], o30 = s[5] + s[6] + s[7];
            const float o01 = s[8], o11 = s[9] + s[10] + s[11];
            const float o21 = s[12], o31 = s[13] + s[14] + s[15];
            const float x0 = s[0] + s[1] + s[2] + s[3];
            const float x1 = s[4] + s[5] + s[6] + s[7];
            const float x2 = s[8] + s[9] + s[10] + s[11];
            const float x3 = s[12] + s[13] + s[14] + s[15];
            const float e0 = __shfl_xor(h ? x0 : o20, 32);
            const float e1 = __shfl_xor(h ? x1 : o30, 32);
            const float e2 = __shfl_xor(h ? x2 : o21, 32);
            const float e3 = __shfl_xor(h ? x3 : o31, 32);
            if (h == 0) {
                const float z00 = sqrtf(fmaxf(o00,      1e-4f));
                const float z10 = sqrtf(fmaxf(o10,      1e-4f));
                const float z20 = sqrtf(fmaxf(o20 + e0, 1e-4f));
                const float z30 = sqrtf(fmaxf(o30 + e1, 1e-4f));
                const float z01 = sqrtf(fmaxf(o01,      1e-4f));
                const float z11 = sqrtf(fmaxf(o11,      1e-4f));
                const float z21 = sqrtf(fmaxf(o21 + e2, 1e-4f));
                const float z31 = sqrtf(fmaxf(o31 + e3, 1e-4f));
                uint4 d;
                d.x = cvt_pk(z00, z10);
                d.y = cvt_pk(z20, z30);
                d.z = cvt_pk(z01, z11);
                d.w = cvt_pk(z21, z31);
                *(uint4*)&zbf[g][(n31 + 32 * ct) * 8] = d;   // j = c*8+r*4+l
            }
        }
    }
    __syncthreads();   // zbf complete, visible to all waves

    // ------- Phase 2: MFMA 16x16x32, D[m=g][n=i], K=512, B = bf16 global ---
    const int m15 = lane & 15;          // A row g AND D col i
    const int q   = lane >> 4;          // k-quad
    f32x4 pa0, pa1;
    #pragma unroll
    for (int j = 0; j < 4; ++j) { pa0[j] = 0.f; pa1[j] = 0.f; }
    const int i0 = w * 32 + m15;
    const int i1 = w * 32 + 16 + m15;
    #pragma unroll 4
    for (int ks = 0; ks < 16; ++ks) {
        U8 Az, Bw0, Bw1;
        Az.q  = *(const uint4*)&zbf[m15][ks * 32 + q * 8];
        Bw0.q = *(const uint4*)&Wb[(size_t)i0 * 512 + ks * 32 + q * 8];
        Bw1.q = *(const uint4*)&Wb[(size_t)i1 * 512 + ks * 32 + q * 8];
        pa0 = __builtin_amdgcn_mfma_f32_16x16x32_bf16(Az.v, Bw0.v, pa0, 0, 0, 0);
        pa1 = __builtin_amdgcn_mfma_f32_16x16x32_bf16(Az.v, Bw1.v, pa1, 0, 0, 0);
    }
    const float bi0 = bias[i0], bi1 = bias[i1];
    #pragma unroll
    for (int reg = 0; reg < 4; ++reg) {
        const int g = q * 4 + reg;                       // D row = g
        const size_t row = ((size_t)b * kV + v_base + g) * 128;
        out[row + i0] = fmaxf(pa0[reg] + bi0, 0.f);
        out[row + i1] = fmaxf(pa1[reg] + bi1, 0.f);
    }
}

} // namespace

extern "C" void kernel_launch(void* const* d_in, const int* in_sizes, int n_in,
                              void* d_out, int out_size, void* d_ws, size_t ws_size,
                              hipStream_t stream) {
    const float* signal = (const float*)d_in[0];
    const int*   pidx   = (const int*)d_in[1];
    const float* ck     = (const float*)d_in[2];
    const float* W      = (const float*)d_in[3];
    const float* bias   = (const float*)d_in[4];
    float* out = (float*)d_out;
    unsigned* Wb = (unsigned*)d_ws;     // 128 KB bf16 weights

    convW<<<dim3(128), dim3(256), 0, stream>>>(W, Wb);
    fused<<<dim3(kBlocks), dim3(256), 0, stream>>>(
        signal, pidx, ck, (const unsigned short*)Wb, bias, out);
}